// Round 14
// baseline (332.099 us; speedup 1.0000x reference)
//
#include <hip/hip_runtime.h>
#include <hip/hip_bf16.h>

// Problem constants (from reference)
#define NB      100000    // B*N nodes
#define NPB     25000     // N per batch
#define T_E     800000    // B*E total edges
#define EPG     200000    // E per graph
#define DMODEL  128       // OUT = H*DH
#define EDIM    32
#define FFD     256
#define SCAN_NBLK 98      // ceil(NB/1024)
#define PROJ_BLK  1563    // ceil(NB/64)
#define NT_E      50000   // T_E/16 edge tiles
#define PHA_GRP   1584    // phase-A groups of 4 blocks (proj|eproj|hist|hist)
#define PHA_BLK   (PHA_GRP * 4)

typedef __attribute__((ext_vector_type(8))) short bf16x8;
typedef __attribute__((ext_vector_type(4))) float f32x4;
typedef __attribute__((ext_vector_type(2))) float f32x2;

__device__ inline unsigned short f2bf(float f) {
    unsigned u = __float_as_uint(f);
    unsigned r = u + 0x7fffu + ((u >> 16) & 1u);   // RNE
    return (unsigned short)(r >> 16);
}
__device__ inline unsigned pack_bf16x2(float lo, float hi) {
    return (unsigned)f2bf(lo) | ((unsigned)f2bf(hi) << 16);
}
__device__ inline float bf_lo(unsigned p) { return __uint_as_float(p << 16); }
__device__ inline float bf_hi(unsigned p) { return __uint_as_float(p & 0xffff0000u); }

// -------------------------------------------------------------------------
// Kernel: pre-pack weights into MFMA A-fragment layout (bf16).
// frags 0..63 w1f | 64..127 w2f | 128..135 wef | 136..263 wpf (Wq,Wk,Wv,Wskip)
// -------------------------------------------------------------------------
__global__ __launch_bounds__(256) void k_prep(
    const float* __restrict__ W1, const float* __restrict__ W2,
    const float* __restrict__ We,
    const float* __restrict__ Wq, const float* __restrict__ Wk,
    const float* __restrict__ Wv, const float* __restrict__ Wskip,
    uint4* __restrict__ w1f, uint4* __restrict__ w2f,
    uint4* __restrict__ wef, uint4* __restrict__ wpf)
{
    int t = blockIdx.x * 256 + threadIdx.x;   // 0..16895
    int lane = t & 63;
    int frag = t >> 6;                         // 0..263
    if (frag >= 264) return;
    int rl = lane & 15, g = lane >> 4;
    unsigned v[4];
    if (frag < 64) {
        int m1 = frag >> 2, ks = frag & 3;
        int col1 = m1 * 16 + rl;
        int k0 = ks * 32 + g * 8;
#pragma unroll
        for (int j2 = 0; j2 < 4; ++j2) {
            float f0 = W1[(k0 + 2 * j2) * FFD + col1];
            float f1 = W1[(k0 + 2 * j2 + 1) * FFD + col1];
            v[j2] = pack_bf16x2(f0, f1);
        }
        w1f[frag * 64 + lane] = make_uint4(v[0], v[1], v[2], v[3]);
    } else if (frag < 128) {
        int f2 = frag - 64;
        int m2 = f2 >> 3, ks = f2 & 7;
        int c2 = m2 * 16 + rl;
        int k0 = ks * 32 + g * 8;
#pragma unroll
        for (int j2 = 0; j2 < 4; ++j2) {
            float f0 = W2[(k0 + 2 * j2) * DMODEL + c2];
            float f1 = W2[(k0 + 2 * j2 + 1) * DMODEL + c2];
            v[j2] = pack_bf16x2(f0, f1);
        }
        w2f[f2 * 64 + lane] = make_uint4(v[0], v[1], v[2], v[3]);
    } else if (frag < 136) {
        int m = frag - 128;                    // 0..7
        int ocol = m * 16 + rl;
        int k0 = g * 8;
#pragma unroll
        for (int j2 = 0; j2 < 4; ++j2) {
            float f0 = We[(k0 + 2 * j2) * DMODEL + ocol];
            float f1 = We[(k0 + 2 * j2 + 1) * DMODEL + ocol];
            v[j2] = pack_bf16x2(f0, f1);
        }
        wef[m * 64 + lane] = make_uint4(v[0], v[1], v[2], v[3]);
    } else {
        int fi = frag - 136;                   // 0..127
        int m  = fi >> 5;                      // matrix 0..3
        int r  = fi & 31;
        int ct = r >> 2, ks = r & 3;
        const float* W = (m == 0) ? Wq : (m == 1) ? Wk : (m == 2) ? Wv : Wskip;
        int col = ct * 16 + rl;
        int k0  = ks * 32 + g * 8;
#pragma unroll
        for (int j2 = 0; j2 < 4; ++j2) {
            float f0 = W[(k0 + 2 * j2) * DMODEL + col];
            float f1 = W[(k0 + 2 * j2 + 1) * DMODEL + col];
            v[j2] = pack_bf16x2(f0, f1);
        }
        wpf[fi * 64 + lane] = make_uint4(v[0], v[1], v[2], v[3]);
    }
}

// -------------------------------------------------------------------------
// PHASE A (3-way fused, modulo-interleaved roles so every CU holds a mix):
//   bid&3 == 0 -> node projections (MFMA, coalesced writes)
//   bid&3 == 1 -> e-projection (MFMA -> eb fp8, LDS transpose, prefetch)
//   bid&3 >= 2 -> degree histogram
// -------------------------------------------------------------------------
#define STG 16384

__global__ __launch_bounds__(256) void k_phaseA(
    const float* __restrict__ x, const uint4* __restrict__ wpf,
    const float* __restrict__ bq, const float* __restrict__ bk,
    const float* __restrict__ bv, const float* __restrict__ bskip,
    unsigned short* __restrict__ qb16, unsigned short* __restrict__ kvb,
    unsigned short* __restrict__ skipb16,
    const float* __restrict__ eattr, const uint4* __restrict__ wef,
    unsigned char* __restrict__ eb,
    const int* __restrict__ eidx, int* __restrict__ counts)
{
    __shared__ __align__(16) char lds[32768];
    const int tid  = threadIdx.x;
    const int role = blockIdx.x & 3;

    if (role >= 2) {
        // ---------------- histogram ----------------
        int hid = (blockIdx.x >> 2) * 2 + (blockIdx.x & 1);
        int t = hid * 256 + tid;
        if (t < T_E) {
            int b = t / EPG, e = t - b * EPG;
            int dst = eidx[(size_t)(b * 2 + 1) * EPG + e];
            atomicAdd(&counts[dst], 1);
        }
        return;
    }

    const int w = tid >> 6, lane = tid & 63;
    const int rl = lane & 15, g = lane >> 4;

    if (role == 1) {
        // ---------------- e-projection (prefetched) ----------------
        char* myl = &lds[w * 2048];
        bf16x8 a[8];
#pragma unroll
        for (int m = 0; m < 8; ++m) a[m] = *(const bf16x8*)&wef[m * 64 + lane];

        const int stride = PHA_GRP * 4;
        int tile = (blockIdx.x >> 2) * 4 + w;
        if (tile >= NT_E) return;
        const float* ep = &eattr[((size_t)tile * 16 + rl) * EDIM + g * 8];
        float4 f0 = *(const float4*)ep;
        float4 f1 = *(const float4*)(ep + 4);
        while (tile < NT_E) {
            int tnext = tile + stride;
            float4 nf0, nf1;
            if (tnext < NT_E) {
                const float* np = &eattr[((size_t)tnext * 16 + rl) * EDIM + g * 8];
                nf0 = *(const float4*)np;
                nf1 = *(const float4*)(np + 4);
            }
            uint4 bu = make_uint4(pack_bf16x2(f0.x, f0.y), pack_bf16x2(f0.z, f0.w),
                                  pack_bf16x2(f1.x, f1.y), pack_bf16x2(f1.z, f1.w));
            bf16x8 b = *(bf16x8*)&bu;
            f32x4 z = {0.f, 0.f, 0.f, 0.f};
            f32x4 acc[8];
#pragma unroll
            for (int m = 0; m < 8; ++m)
                acc[m] = __builtin_amdgcn_mfma_f32_16x16x32_bf16(a[m], b, z, 0, 0, 0);
#pragma unroll
            for (int m = 0; m < 8; ++m) {
                unsigned d = __builtin_amdgcn_cvt_pk_fp8_f32(acc[m][0], acc[m][1], 0, false);
                d = __builtin_amdgcn_cvt_pk_fp8_f32(acc[m][2], acc[m][3], d, true);
                *(unsigned*)(myl + rl * 128 + ((m * 16) ^ ((rl & 7) << 4)) + g * 4) = d;
            }
#pragma unroll
            for (int it = 0; it < 2; ++it) {
                int lin = it * 64 + lane;
                int row = lin >> 3, chunk = lin & 7;
                uint4 vv = *(const uint4*)(myl + row * 128 + ((chunk ^ (row & 7)) << 4));
                *(uint4*)&eb[(size_t)tile * 2048 + (size_t)lin * 16] = vv;
            }
            tile = tnext;
            f0 = nf0;
            f1 = nf1;
        }
        return;
    }

    // ---------------- node projections ----------------
    const int pid = blockIdx.x >> 2;
    if (pid >= PROJ_BLK) return;
    const int node0 = pid * 64;

    {
        const int nl   = tid & 63;
        const int half = tid >> 6;             // 0..3
        const int node = node0 + nl;
        const bool valid = node < NB;
        int b  = node / NPB;
        int nn = node - b * NPB;
        const float* xbase = x + (size_t)b * DMODEL * NPB + nn;
#pragma unroll
        for (int o = 0; o < 4; ++o) {
            int c0 = (half * 4 + o) * 8;
            unsigned vals[4];
#pragma unroll
            for (int j2 = 0; j2 < 4; ++j2) {
                float f0 = valid ? xbase[(size_t)(c0 + 2 * j2) * NPB] : 0.f;
                float f1 = valid ? xbase[(size_t)(c0 + 2 * j2 + 1) * NPB] : 0.f;
                vals[j2] = pack_bf16x2(f0, f1);
            }
            int byte = nl * 256 + ((c0 * 2) ^ ((nl & 7) << 4));
            *(uint4*)(&lds[byte]) = make_uint4(vals[0], vals[1], vals[2], vals[3]);
        }
    }
    __syncthreads();

    for (int m = 0; m < 4; ++m) {
        const float* bi = (m == 0) ? bq : (m == 1) ? bk : (m == 2) ? bv : bskip;
#pragma unroll
        for (int ct2 = 0; ct2 < 2; ++ct2) {
            const int ct = w * 2 + ct2;
            bf16x8 A[4];
#pragma unroll
            for (int ks = 0; ks < 4; ++ks)
                A[ks] = *(const bf16x8*)&wpf[((m * 8 + ct) * 4 + ks) * 64 + lane];
            const int colb = ct * 16 + g * 4;
            const float bb0 = bi[colb], bb1 = bi[colb + 1],
                        bb2 = bi[colb + 2], bb3 = bi[colb + 3];
#pragma unroll
            for (int nt = 0; nt < 4; ++nt) {
                const int nl = nt * 16 + rl;
                f32x4 acc = {0.f, 0.f, 0.f, 0.f};
#pragma unroll
                for (int ks = 0; ks < 4; ++ks) {
                    bf16x8 B = *(const bf16x8*)(&lds[nl * 256 +
                                  ((ks * 64 + g * 16) ^ ((nl & 7) << 4))]);
                    acc = __builtin_amdgcn_mfma_f32_16x16x32_bf16(A[ks], B, acc, 0, 0, 0);
                }
                unsigned lo = pack_bf16x2(acc[0] + bb0, acc[1] + bb1);
                unsigned hi = pack_bf16x2(acc[2] + bb2, acc[3] + bb3);
                int byte = STG + nl * 256 + ((colb * 2) ^ ((nl & 7) << 4));
                *(uint2*)(&lds[byte]) = make_uint2(lo, hi);
            }
        }
        __syncthreads();
#pragma unroll
        for (int i = 0; i < 4; ++i) {
            int linear = i * 256 + tid;
            int row = linear >> 4;
            int c8  = (linear & 15) * 8;
            int node = node0 + row;
            if (node < NB) {
                uint4 vv = *(const uint4*)(&lds[STG + row * 256 +
                                ((c8 * 2) ^ ((row & 7) << 4))]);
                if (m == 0)      *(uint4*)&qb16[(size_t)node * DMODEL + c8] = vv;
                else if (m == 1) *(uint4*)&kvb[(size_t)node * 256 + c8] = vv;
                else if (m == 2) *(uint4*)&kvb[(size_t)node * 256 + 128 + c8] = vv;
                else             *(uint4*)&skipb16[(size_t)node * DMODEL + c8] = vv;
            }
        }
        __syncthreads();
    }
}

// -------------------------------------------------------------------------
// Scan chain (3 kernels) + scatter.
// -------------------------------------------------------------------------
__global__ __launch_bounds__(1024) void k_scan1(
    const int* __restrict__ counts, int* __restrict__ row_start,
    int* __restrict__ bsum)
{
    __shared__ int s[1024];
    const int tid = threadIdx.x;
    const int gid = blockIdx.x * 1024 + tid;
    int v = (gid < NB) ? counts[gid] : 0;
    s[tid] = v;
    __syncthreads();
#pragma unroll
    for (int off = 1; off < 1024; off <<= 1) {
        int tv = (tid >= off) ? s[tid - off] : 0;
        __syncthreads();
        s[tid] += tv;
        __syncthreads();
    }
    int incl = s[tid];
    if (gid < NB) row_start[gid] = incl - v;
    if (tid == 1023) bsum[blockIdx.x] = incl;
}

__global__ __launch_bounds__(128) void k_scan2(int* __restrict__ bsum)
{
    __shared__ int s[128];
    const int tid = threadIdx.x;
    int v = (tid < SCAN_NBLK) ? bsum[tid] : 0;
    s[tid] = v;
    __syncthreads();
#pragma unroll
    for (int off = 1; off < 128; off <<= 1) {
        int tv = (tid >= off) ? s[tid - off] : 0;
        __syncthreads();
        s[tid] += tv;
        __syncthreads();
    }
    if (tid < SCAN_NBLK) bsum[tid] = s[tid] - v;
}

__global__ __launch_bounds__(1024) void k_scan3(
    int* __restrict__ row_start, const int* __restrict__ bsum,
    int* __restrict__ cursor)
{
    const int gid = blockIdx.x * 1024 + threadIdx.x;
    if (gid < NB) {
        int v = row_start[gid] + bsum[blockIdx.x];
        row_start[gid] = v;
        cursor[gid] = v;
    }
}

__global__ __launch_bounds__(256) void k_scatter(
    const int* __restrict__ eidx, int* __restrict__ cursor,
    int2* __restrict__ elist2)
{
    int t = blockIdx.x * 256 + threadIdx.x;
    if (t < T_E) {
        int b = t / EPG, e = t - b * EPG;
        int dst = eidx[(size_t)(b * 2 + 1) * EPG + e];
        int src = eidx[(size_t)(b * 2) * EPG + e];
        int pos = atomicAdd(&cursor[dst], 1);
        elist2[pos] = make_int2(src, t);   // after: cursor[d] == row_end[d]
    }
}

// -------------------------------------------------------------------------
// Kernel: per-node gather-aggregate, 8 edges in flight per wave
// (2 quads of quarter-waves), 8 channels per lane, eb fp8 e-add.
// Output: xs16[node][c] = agg_norm + skip (bf16) — into qb16 space.
// -------------------------------------------------------------------------
__global__ __launch_bounds__(256) void k_aggr3(
    unsigned short* qx,                       // q (read) / xs16 (write) — aliased
    const unsigned short* __restrict__ kvb,
    const unsigned short* __restrict__ skipb16,
    const unsigned char* __restrict__ eb,
    const int2* __restrict__ elist2,
    const int* __restrict__ row_start, const int* __restrict__ row_end)
{
    const int tid = threadIdx.x;
    const int w = tid >> 6, l = tid & 63;
    const int q4 = l >> 4;                    // which edge of the quad
    const int li = l & 15;
    const int c0 = li * 8;                    // this lane's 8 channels

    const int nwaves = gridDim.x * 4;
    for (int node = blockIdx.x * 4 + w; node < NB; node += nwaves) {
        const int rs = row_start[node];
        const int re = row_end[node];
        uint4 qp = *(const uint4*)&qx[(size_t)node * DMODEL + c0];
        const float q0 = bf_lo(qp.x), q1 = bf_hi(qp.x);
        const float q2 = bf_lo(qp.y), q3 = bf_hi(qp.y);
        const float q4_ = bf_lo(qp.z), q5 = bf_hi(qp.z);
        const float q6 = bf_lo(qp.w), q7 = bf_hi(qp.w);
        float a0 = 0.f, a1 = 0.f, a2 = 0.f, a3 = 0.f;
        float a4 = 0.f, a5 = 0.f, a6 = 0.f, a7 = 0.f, den = 0.f;

        for (int j0 = rs; j0 < re; j0 += 8) {
            const int jcA = j0 + q4;
            const int jcB = j0 + 4 + q4;
            const bool actA = jcA < re;        // uniform across 16-lane group
            const bool actB = jcB < re;
            uint4 kpA = make_uint4(0,0,0,0), vpA = make_uint4(0,0,0,0);
            uint4 kpB = make_uint4(0,0,0,0), vpB = make_uint4(0,0,0,0);
            uint2 epA = make_uint2(0,0), epB = make_uint2(0,0);
            if (actA) {
                int2 se = elist2[jcA];
                kpA = *(const uint4*)&kvb[(size_t)se.x * 256 + c0];
                vpA = *(const uint4*)&kvb[(size_t)se.x * 256 + 128 + c0];
                epA = *(const uint2*)&eb[(size_t)se.y * DMODEL + c0];
            }
            if (actB) {
                int2 se = elist2[jcB];
                kpB = *(const uint4*)&kvb[(size_t)se.x * 256 + c0];
                vpB = *(const uint4*)&kvb[(size_t)se.x * 256 + 128 + c0];
                epB = *(const uint2*)&eb[(size_t)se.y * DMODEL + c0];
            }
            // ---- quad A
            {
                f32x2 exl = __builtin_amdgcn_cvt_pk_f32_fp8(epA.x, false);
                f32x2 exh = __builtin_amdgcn_cvt_pk_f32_fp8(epA.x, true);
                f32x2 eyl = __builtin_amdgcn_cvt_pk_f32_fp8(epA.y, false);
                f32x2 eyh = __builtin_amdgcn_cvt_pk_f32_fp8(epA.y, true);
                const float e0 = exl[0], e1 = exl[1], e2 = exh[0], e3 = exh[1];
                const float e4 = eyl[0], e5 = eyl[1], e6 = eyh[0], e7 = eyh[1];
                float p = q0 * (bf_lo(kpA.x) + e0) + q1 * (bf_hi(kpA.x) + e1)
                        + q2 * (bf_lo(kpA.y) + e2) + q3 * (bf_hi(kpA.y) + e3)
                        + q4_ * (bf_lo(kpA.z) + e4) + q5 * (bf_hi(kpA.z) + e5)
                        + q6 * (bf_lo(kpA.w) + e6) + q7 * (bf_hi(kpA.w) + e7);
                p += __shfl_xor(p, 1, 64);
                p += __shfl_xor(p, 2, 64);
                float ea = actA ? __expf(p * 0.17677669529663689f) : 0.f;
                a0 += ea * (bf_lo(vpA.x) + e0);  a1 += ea * (bf_hi(vpA.x) + e1);
                a2 += ea * (bf_lo(vpA.y) + e2);  a3 += ea * (bf_hi(vpA.y) + e3);
                a4 += ea * (bf_lo(vpA.z) + e4);  a5 += ea * (bf_hi(vpA.z) + e5);
                a6 += ea * (bf_lo(vpA.w) + e6);  a7 += ea * (bf_hi(vpA.w) + e7);
                den += ea;
            }
            // ---- quad B
            {
                f32x2 exl = __builtin_amdgcn_cvt_pk_f32_fp8(epB.x, false);
                f32x2 exh = __builtin_amdgcn_cvt_pk_f32_fp8(epB.x, true);
                f32x2 eyl = __builtin_amdgcn_cvt_pk_f32_fp8(epB.y, false);
                f32x2 eyh = __builtin_amdgcn_cvt_pk_f32_fp8(epB.y, true);
                const float e0 = exl[0], e1 = exl[1], e2 = exh[0], e3 = exh[1];
                const float e4 = eyl[0], e5 = eyl[1], e6 = eyh[0], e7 = eyh[1];
                float p = q0 * (bf_lo(kpB.x) + e0) + q1 * (bf_hi(kpB.x) + e1)
                        + q2 * (bf_lo(kpB.y) + e2) + q3 * (bf_hi(kpB.y) + e3)
                        + q4_ * (bf_lo(kpB.z) + e4) + q5 * (bf_hi(kpB.z) + e5)
                        + q6 * (bf_lo(kpB.w) + e6) + q7 * (bf_hi(kpB.w) + e7);
                p += __shfl_xor(p, 1, 64);
                p += __shfl_xor(p, 2, 64);
                float ea = actB ? __expf(p * 0.17677669529663689f) : 0.f;
                a0 += ea * (bf_lo(vpB.x) + e0);  a1 += ea * (bf_hi(vpB.x) + e1);
                a2 += ea * (bf_lo(vpB.y) + e2);  a3 += ea * (bf_hi(vpB.y) + e3);
                a4 += ea * (bf_lo(vpB.z) + e4);  a5 += ea * (bf_hi(vpB.z) + e5);
                a6 += ea * (bf_lo(vpB.w) + e6);  a7 += ea * (bf_hi(vpB.w) + e7);
                den += ea;
            }
        }
        // combine the four quarter-wave edge streams
#pragma unroll
        for (int off = 16; off <= 32; off <<= 1) {
            a0 += __shfl_xor(a0, off, 64);  a1 += __shfl_xor(a1, off, 64);
            a2 += __shfl_xor(a2, off, 64);  a3 += __shfl_xor(a3, off, 64);
            a4 += __shfl_xor(a4, off, 64);  a5 += __shfl_xor(a5, off, 64);
            a6 += __shfl_xor(a6, off, 64);  a7 += __shfl_xor(a7, off, 64);
            den += __shfl_xor(den, off, 64);
        }
        float r = 1.0f / (den + 1e-16f);
        if (q4 == 0) {
            uint4 sp = *(const uint4*)&skipb16[(size_t)node * DMODEL + c0];
            uint4 o;
            o.x = pack_bf16x2(a0 * r + bf_lo(sp.x), a1 * r + bf_hi(sp.x));
            o.y = pack_bf16x2(a2 * r + bf_lo(sp.y), a3 * r + bf_hi(sp.y));
            o.z = pack_bf16x2(a4 * r + bf_lo(sp.z), a5 * r + bf_hi(sp.z));
            o.w = pack_bf16x2(a6 * r + bf_lo(sp.w), a7 * r + bf_hi(sp.w));
            *(uint4*)&qx[(size_t)node * DMODEL + c0] = o;
        }
    }
}

// -------------------------------------------------------------------------
// Kernel (MFMA): FFN on xs16 (= agg_norm + skip, bf16) + transposed write.
// -------------------------------------------------------------------------
#define H1_OFF 16384

__global__ __launch_bounds__(256) void k_ffn_mfma(
    const unsigned short* __restrict__ xs16,
    const uint4* __restrict__ w1f, const float* __restrict__ b1,
    const uint4* __restrict__ w2f, const float* __restrict__ b2,
    float* __restrict__ out)
{
    __shared__ __align__(16) char lds[49152];
    const int tid   = threadIdx.x;
    const int node0 = blockIdx.x * 64;

#pragma unroll
    for (int i = 0; i < 4; ++i) {
        int linear = i * 256 + tid;
        int row = linear >> 4;
        int c8  = (linear & 15) * 8;
        int node = node0 + row;
        uint4 vv = (node < NB) ? *(const uint4*)&xs16[(size_t)node * DMODEL + c8]
                               : make_uint4(0, 0, 0, 0);
        int byte = row * 256 + ((c8 * 2) ^ ((row & 7) << 4));
        *(uint4*)(&lds[byte]) = vv;
    }
    __syncthreads();

    const int w = tid >> 6, lane = tid & 63;
    const int rl = lane & 15, g = lane >> 4;

    // ---- GEMM1: wave w covers col1 in [w*64, w*64+64)
    {
        f32x4 acc[4][4] = {};
#pragma unroll
        for (int ks = 0; ks < 4; ++ks) {
            bf16x8 a[4], b[4];
#pragma unroll
            for (int mt = 0; mt < 4; ++mt) {
                int m1 = w * 4 + mt;
                a[mt] = *(const bf16x8*)&w1f[(m1 * 4 + ks) * 64 + lane];
            }
#pragma unroll
            for (int nt = 0; nt < 4; ++nt) {
                int node = nt * 16 + rl;
                int byte = node * 256 + ((ks * 64 + g * 16) ^ ((node & 7) << 4));
                b[nt] = *(const bf16x8*)&lds[byte];
            }
#pragma unroll
            for (int mt = 0; mt < 4; ++mt)
#pragma unroll
                for (int nt = 0; nt < 4; ++nt)
                    acc[mt][nt] = __builtin_amdgcn_mfma_f32_16x16x32_bf16(
                        a[mt], b[nt], acc[mt][nt], 0, 0, 0);
        }
#pragma unroll
        for (int mt = 0; mt < 4; ++mt) {
            int col1_0 = w * 64 + mt * 16 + g * 4;
            float bb0 = b1[col1_0], bb1 = b1[col1_0 + 1],
                  bb2 = b1[col1_0 + 2], bb3 = b1[col1_0 + 3];
#pragma unroll
            for (int nt = 0; nt < 4; ++nt) {
                int node = nt * 16 + rl;
                float v0 = fmaxf(acc[mt][nt][0] + bb0, 0.f);
                float v1 = fmaxf(acc[mt][nt][1] + bb1, 0.f);
                float v2 = fmaxf(acc[mt][nt][2] + bb2, 0.f);
                float v3 = fmaxf(acc[mt][nt][3] + bb3, 0.f);
                unsigned lo = pack_bf16x2(v0, v1), hi = pack_bf16x2(v2, v3);
                int byte = H1_OFF + node * 512 + ((col1_0 * 2) ^ ((node & 7) << 4));
                *(uint2*)(&lds[byte]) = make_uint2(lo, hi);
            }
        }
    }
    __syncthreads();

    // ---- GEMM2: wave w covers c2 in [w*32, w*32+32)
    {
        f32x4 acc[2][4] = {};
#pragma unroll
        for (int ks = 0; ks < 8; ++ks) {
            bf16x8 a[2], b[4];
#pragma unroll
            for (int mt = 0; mt < 2; ++mt) {
                int m2 = w * 2 + mt;
                a[mt] = *(const bf16x8*)&w2f[(m2 * 8 + ks) * 64 + lane];
            }
#pragma unroll
            for (int nt = 0; nt < 4; ++nt) {
                int node = nt * 16 + rl;
                int byte = H1_OFF + node * 512 + ((ks * 64 + g * 16) ^ ((node & 7) << 4));
                b[nt] = *(const bf16x8*)&lds[byte];
            }
#pragma unroll
            for (int mt = 0; mt < 2; ++mt)
#pragma unroll
                for (int nt = 0; nt < 4; ++nt)
                    acc[mt][nt] = __builtin_amdgcn_mfma_f32_16x16x32_bf16(
                        a[mt], b[nt], acc[mt][nt], 0, 0, 0);
        }
#pragma unroll
        for (int mt = 0; mt < 2; ++mt) {
            int c2_0 = w * 32 + mt * 16 + g * 4;
#pragma unroll
            for (int nt = 0; nt < 4; ++nt) {
                int node = node0 + nt * 16 + rl;
                if (node < NB) {
                    int bb = node / NPB;
                    int nn = node - bb * NPB;
                    size_t base = (size_t)(bb * DMODEL) * NPB + nn;
#pragma unroll
                    for (int r = 0; r < 4; ++r) {
                        float v = fmaxf(acc[mt][nt][r] + b2[c2_0 + r], 0.f);
                        out[base + (size_t)(c2_0 + r) * NPB] = v;
                    }
                }
            }
        }
    }
}

// -------------------------------------------------------------------------
extern "C" void kernel_launch(void* const* d_in, const int* in_sizes, int n_in,
                              void* d_out, int out_size, void* d_ws, size_t ws_size,
                              hipStream_t stream)
{
    const float* x     = (const float*)d_in[0];
    const int*   eidx  = (const int*)  d_in[1];
    const float* eattr = (const float*)d_in[2];
    const float* Wq    = (const float*)d_in[3];
    const float* bq    = (const float*)d_in[4];
    const float* Wk    = (const float*)d_in[5];
    const float* bk    = (const float*)d_in[6];
    const float* Wv    = (const float*)d_in[7];
    const float* bv    = (const float*)d_in[8];
    const float* We    = (const float*)d_in[9];
    const float* Wskip = (const float*)d_in[10];
    const float* bskip = (const float*)d_in[11];
    const float* W1    = (const float*)d_in[12];
    const float* b1    = (const float*)d_in[13];
    const float* W2    = (const float*)d_in[14];
    const float* b2    = (const float*)d_in[15];
    float* out = (float*)d_out;

    // ws layout (~212.9 MB, proven budget):
    // qb16(->xs16) | kvb | skipb16 | eb fp8 | w1f | w2f | wef | wpf |
    // counts | row_start | cursor | elist2 | bsum
    const size_t NBD = (size_t)NB * DMODEL;
    unsigned short* qb16    = (unsigned short*)d_ws;
    unsigned short* kvb     = qb16 + NBD;
    unsigned short* skipb16 = kvb + 2 * NBD;
    unsigned char*  eb      = (unsigned char*)(skipb16 + NBD);
    uint4* w1f = (uint4*)(eb + (size_t)T_E * DMODEL);
    uint4* w2f = w1f + 64 * 64;
    uint4* wef = w2f + 64 * 64;
    uint4* wpf = wef + 8 * 64;
    int* counts    = (int*)(wpf + 128 * 64);
    int* row_start = counts + NB;
    int* cursor    = row_start + NB;
    int2* elist2   = (int2*)(cursor + NB);
    int* bsum      = (int*)(elist2 + T_E);

    hipMemsetAsync(counts, 0, NB * sizeof(int), stream);
    k_prep<<<66, 256, 0, stream>>>(W1, W2, We, Wq, Wk, Wv, Wskip,
                                   w1f, w2f, wef, wpf);
    k_phaseA<<<PHA_BLK, 256, 0, stream>>>(
        x, wpf, bq, bk, bv, bskip, qb16, kvb, skipb16,
        eattr, wef, eb, eidx, counts);
    k_scan1<<<SCAN_NBLK, 1024, 0, stream>>>(counts, row_start, bsum);
    k_scan2<<<1, 128, 0, stream>>>(bsum);
    k_scan3<<<SCAN_NBLK, 1024, 0, stream>>>(row_start, bsum, cursor);
    k_scatter<<<(T_E + 255) / 256, 256, 0, stream>>>(eidx, cursor, elist2);
    k_aggr3<<<2048, 256, 0, stream>>>(qb16, kvb, skipb16, eb, elist2,
                                      row_start, cursor);
    k_ffn_mfma<<<(NB + 63) / 64, 256, 0, stream>>>(qb16, w1f, b1, w2f, b2, out);
}

// Round 15
// 302.185 us; speedup vs baseline: 1.0990x; 1.0990x over previous
//
#include <hip/hip_runtime.h>
#include <hip/hip_bf16.h>

// Problem constants (from reference)
#define NB      100000    // B*N nodes
#define NPB     25000     // N per batch
#define T_E     800000    // B*E total edges
#define EPG     200000    // E per graph
#define DMODEL  128       // OUT = H*DH
#define EDIM    32
#define FFD     256
#define SCAN_NBLK 98      // ceil(NB/1024)
#define NT_E      50000   // T_E/16 edge tiles

typedef __attribute__((ext_vector_type(8))) short bf16x8;
typedef __attribute__((ext_vector_type(4))) float f32x4;
typedef __attribute__((ext_vector_type(2))) float f32x2;

__device__ inline unsigned short f2bf(float f) {
    unsigned u = __float_as_uint(f);
    unsigned r = u + 0x7fffu + ((u >> 16) & 1u);   // RNE
    return (unsigned short)(r >> 16);
}
__device__ inline unsigned pack_bf16x2(float lo, float hi) {
    return (unsigned)f2bf(lo) | ((unsigned)f2bf(hi) << 16);
}
__device__ inline float bf_lo(unsigned p) { return __uint_as_float(p << 16); }
__device__ inline float bf_hi(unsigned p) { return __uint_as_float(p & 0xffff0000u); }

// -------------------------------------------------------------------------
// Kernel: pre-pack weights into MFMA A-fragment layout (bf16) + zero counts.
// frags 0..63 w1f | 64..127 w2f | 128..135 wef | 136..263 wpf (Wq,Wk,Wv,Wskip)
// -------------------------------------------------------------------------
__global__ __launch_bounds__(256) void k_prep(
    const float* __restrict__ W1, const float* __restrict__ W2,
    const float* __restrict__ We,
    const float* __restrict__ Wq, const float* __restrict__ Wk,
    const float* __restrict__ Wv, const float* __restrict__ Wskip,
    uint4* __restrict__ w1f, uint4* __restrict__ w2f,
    uint4* __restrict__ wef, uint4* __restrict__ wpf,
    int* __restrict__ counts)
{
    int t = blockIdx.x * 256 + threadIdx.x;   // 0..16895
    // zero CSR counts (grid-stride; replaces hipMemsetAsync launch)
    for (int i = t; i < NB; i += 66 * 256) counts[i] = 0;

    int lane = t & 63;
    int frag = t >> 6;                         // 0..263
    if (frag >= 264) return;
    int rl = lane & 15, g = lane >> 4;
    unsigned v[4];
    if (frag < 64) {
        int m1 = frag >> 2, ks = frag & 3;
        int col1 = m1 * 16 + rl;
        int k0 = ks * 32 + g * 8;
#pragma unroll
        for (int j2 = 0; j2 < 4; ++j2) {
            float f0 = W1[(k0 + 2 * j2) * FFD + col1];
            float f1 = W1[(k0 + 2 * j2 + 1) * FFD + col1];
            v[j2] = pack_bf16x2(f0, f1);
        }
        w1f[frag * 64 + lane] = make_uint4(v[0], v[1], v[2], v[3]);
    } else if (frag < 128) {
        int f2 = frag - 64;
        int m2 = f2 >> 3, ks = f2 & 7;
        int c2 = m2 * 16 + rl;
        int k0 = ks * 32 + g * 8;
#pragma unroll
        for (int j2 = 0; j2 < 4; ++j2) {
            float f0 = W2[(k0 + 2 * j2) * DMODEL + c2];
            float f1 = W2[(k0 + 2 * j2 + 1) * DMODEL + c2];
            v[j2] = pack_bf16x2(f0, f1);
        }
        w2f[f2 * 64 + lane] = make_uint4(v[0], v[1], v[2], v[3]);
    } else if (frag < 136) {
        int m = frag - 128;                    // 0..7
        int ocol = m * 16 + rl;
        int k0 = g * 8;
#pragma unroll
        for (int j2 = 0; j2 < 4; ++j2) {
            float f0 = We[(k0 + 2 * j2) * DMODEL + ocol];
            float f1 = We[(k0 + 2 * j2 + 1) * DMODEL + ocol];
            v[j2] = pack_bf16x2(f0, f1);
        }
        wef[m * 64 + lane] = make_uint4(v[0], v[1], v[2], v[3]);
    } else {
        int fi = frag - 136;                   // 0..127
        int m  = fi >> 5;                      // matrix 0..3
        int r  = fi & 31;
        int ct = r >> 2, ks = r & 3;
        const float* W = (m == 0) ? Wq : (m == 1) ? Wk : (m == 2) ? Wv : Wskip;
        int col = ct * 16 + rl;
        int k0  = ks * 32 + g * 8;
#pragma unroll
        for (int j2 = 0; j2 < 4; ++j2) {
            float f0 = W[(k0 + 2 * j2) * DMODEL + col];
            float f1 = W[(k0 + 2 * j2 + 1) * DMODEL + col];
            v[j2] = pack_bf16x2(f0, f1);
        }
        wpf[fi * 64 + lane] = make_uint4(v[0], v[1], v[2], v[3]);
    }
}

// -------------------------------------------------------------------------
// Kernel (MFMA): node projections, phase-per-matrix with LDS-staged
// COALESCED global writes.  LDS: xs @0 (16 KB), stage @16384 (16 KB).
// -------------------------------------------------------------------------
#define STG 16384

__global__ __launch_bounds__(256) void k_proj2(
    const float* __restrict__ x, const uint4* __restrict__ wpf,
    const float* __restrict__ bq, const float* __restrict__ bk,
    const float* __restrict__ bv, const float* __restrict__ bskip,
    unsigned short* __restrict__ qb16, unsigned short* __restrict__ kvb,
    unsigned short* __restrict__ skipb16)
{
    __shared__ __align__(16) char lds[32768];
    const int tid   = threadIdx.x;
    const int node0 = blockIdx.x * 64;

    // ---- stage xs: x[b,c,nn] -> xs[node_local][c] (bf16, swizzled)
    {
        const int nl   = tid & 63;
        const int half = tid >> 6;             // 0..3
        const int node = node0 + nl;
        const bool valid = node < NB;
        int b  = node / NPB;
        int nn = node - b * NPB;
        const float* xbase = x + (size_t)b * DMODEL * NPB + nn;
#pragma unroll
        for (int o = 0; o < 4; ++o) {
            int c0 = (half * 4 + o) * 8;
            unsigned vals[4];
#pragma unroll
            for (int j2 = 0; j2 < 4; ++j2) {
                float f0 = valid ? xbase[(size_t)(c0 + 2 * j2) * NPB] : 0.f;
                float f1 = valid ? xbase[(size_t)(c0 + 2 * j2 + 1) * NPB] : 0.f;
                vals[j2] = pack_bf16x2(f0, f1);
            }
            int byte = nl * 256 + ((c0 * 2) ^ ((nl & 7) << 4));
            *(uint4*)(&lds[byte]) = make_uint4(vals[0], vals[1], vals[2], vals[3]);
        }
    }
    __syncthreads();

    const int w = tid >> 6, lane = tid & 63;
    const int rl = lane & 15, g = lane >> 4;

    for (int m = 0; m < 4; ++m) {
        const float* bi = (m == 0) ? bq : (m == 1) ? bk : (m == 2) ? bv : bskip;
        // ---- compute cols [w*32, w*32+32): D[col][node], stage into LDS
#pragma unroll
        for (int ct2 = 0; ct2 < 2; ++ct2) {
            const int ct = w * 2 + ct2;
            bf16x8 A[4];
#pragma unroll
            for (int ks = 0; ks < 4; ++ks)
                A[ks] = *(const bf16x8*)&wpf[((m * 8 + ct) * 4 + ks) * 64 + lane];
            const int colb = ct * 16 + g * 4;
            const float bb0 = bi[colb], bb1 = bi[colb + 1],
                        bb2 = bi[colb + 2], bb3 = bi[colb + 3];
#pragma unroll
            for (int nt = 0; nt < 4; ++nt) {
                const int nl = nt * 16 + rl;
                f32x4 acc = {0.f, 0.f, 0.f, 0.f};
#pragma unroll
                for (int ks = 0; ks < 4; ++ks) {
                    bf16x8 B = *(const bf16x8*)(&lds[nl * 256 +
                                  ((ks * 64 + g * 16) ^ ((nl & 7) << 4))]);
                    acc = __builtin_amdgcn_mfma_f32_16x16x32_bf16(A[ks], B, acc, 0, 0, 0);
                }
                unsigned lo = pack_bf16x2(acc[0] + bb0, acc[1] + bb1);
                unsigned hi = pack_bf16x2(acc[2] + bb2, acc[3] + bb3);
                int byte = STG + nl * 256 + ((colb * 2) ^ ((nl & 7) << 4));
                *(uint2*)(&lds[byte]) = make_uint2(lo, hi);
            }
        }
        __syncthreads();
        // ---- coalesced global write (full 256 B rows)
#pragma unroll
        for (int i = 0; i < 4; ++i) {
            int linear = i * 256 + tid;
            int row = linear >> 4;
            int c8  = (linear & 15) * 8;
            int node = node0 + row;
            if (node < NB) {
                uint4 vv = *(const uint4*)(&lds[STG + row * 256 +
                                ((c8 * 2) ^ ((row & 7) << 4))]);
                if (m == 0)      *(uint4*)&qb16[(size_t)node * DMODEL + c8] = vv;
                else if (m == 1) *(uint4*)&kvb[(size_t)node * 256 + c8] = vv;
                else if (m == 2) *(uint4*)&kvb[(size_t)node * 256 + 128 + c8] = vv;
                else             *(uint4*)&skipb16[(size_t)node * DMODEL + c8] = vv;
            }
        }
        __syncthreads();
    }
}

// -------------------------------------------------------------------------
// CSR build: histogram -> scan (3 kernels) -> scatter.
// -------------------------------------------------------------------------
__global__ __launch_bounds__(256) void k_hist(
    const int* __restrict__ eidx, int* __restrict__ counts)
{
    int t = blockIdx.x * 256 + threadIdx.x;
    if (t < T_E) {
        int b = t / EPG, e = t - b * EPG;
        int dst = eidx[(size_t)(b * 2 + 1) * EPG + e];
        atomicAdd(&counts[dst], 1);
    }
}

__global__ __launch_bounds__(1024) void k_scan1(
    const int* __restrict__ counts, int* __restrict__ row_start,
    int* __restrict__ bsum)
{
    __shared__ int s[1024];
    const int tid = threadIdx.x;
    const int gid = blockIdx.x * 1024 + tid;
    int v = (gid < NB) ? counts[gid] : 0;
    s[tid] = v;
    __syncthreads();
#pragma unroll
    for (int off = 1; off < 1024; off <<= 1) {
        int tv = (tid >= off) ? s[tid - off] : 0;
        __syncthreads();
        s[tid] += tv;
        __syncthreads();
    }
    int incl = s[tid];
    if (gid < NB) row_start[gid] = incl - v;
    if (tid == 1023) bsum[blockIdx.x] = incl;
}

__global__ __launch_bounds__(128) void k_scan2(int* __restrict__ bsum)
{
    __shared__ int s[128];
    const int tid = threadIdx.x;
    int v = (tid < SCAN_NBLK) ? bsum[tid] : 0;
    s[tid] = v;
    __syncthreads();
#pragma unroll
    for (int off = 1; off < 128; off <<= 1) {
        int tv = (tid >= off) ? s[tid - off] : 0;
        __syncthreads();
        s[tid] += tv;
        __syncthreads();
    }
    if (tid < SCAN_NBLK) bsum[tid] = s[tid] - v;
}

__global__ __launch_bounds__(1024) void k_scan3(
    int* __restrict__ row_start, const int* __restrict__ bsum,
    int* __restrict__ cursor)
{
    const int gid = blockIdx.x * 1024 + threadIdx.x;
    if (gid < NB) {
        int v = row_start[gid] + bsum[blockIdx.x];
        row_start[gid] = v;
        cursor[gid] = v;
    }
}

__global__ __launch_bounds__(256) void k_scatter(
    const int* __restrict__ eidx, int* __restrict__ cursor,
    int2* __restrict__ elist2)
{
    int t = blockIdx.x * 256 + threadIdx.x;
    if (t < T_E) {
        int b = t / EPG, e = t - b * EPG;
        int dst = eidx[(size_t)(b * 2 + 1) * EPG + e];
        int src = eidx[(size_t)(b * 2) * EPG + e];
        int pos = atomicAdd(&cursor[dst], 1);
        elist2[pos] = make_int2(src, t);   // after: cursor[d] == row_end[d]
    }
}

// -------------------------------------------------------------------------
// Kernel: e-projection, edge-parallel MFMA -> eb fp8, wave-private LDS
// transpose for coalesced stores, software-prefetched eattr.
// -------------------------------------------------------------------------
__global__ __launch_bounds__(256) void k_eproj(
    const float* __restrict__ eattr, const uint4* __restrict__ wef,
    unsigned char* __restrict__ eb)
{
    __shared__ __align__(16) char elds[8192];   // 4 waves x 2 KB
    const int tid = threadIdx.x;
    const int w = tid >> 6, lane = tid & 63;
    const int rl = lane & 15, g = lane >> 4;
    char* myl = &elds[w * 2048];

    bf16x8 a[8];
#pragma unroll
    for (int m = 0; m < 8; ++m) a[m] = *(const bf16x8*)&wef[m * 64 + lane];

    const int stride = 2048 * 4;
    int tile = blockIdx.x * 4 + w;
    if (tile >= NT_E) return;
    const float* ep = &eattr[((size_t)tile * 16 + rl) * EDIM + g * 8];
    float4 f0 = *(const float4*)ep;
    float4 f1 = *(const float4*)(ep + 4);
    while (tile < NT_E) {
        int tnext = tile + stride;
        float4 nf0, nf1;
        if (tnext < NT_E) {
            const float* np = &eattr[((size_t)tnext * 16 + rl) * EDIM + g * 8];
            nf0 = *(const float4*)np;
            nf1 = *(const float4*)(np + 4);
        }
        uint4 bu = make_uint4(pack_bf16x2(f0.x, f0.y), pack_bf16x2(f0.z, f0.w),
                              pack_bf16x2(f1.x, f1.y), pack_bf16x2(f1.z, f1.w));
        bf16x8 b = *(bf16x8*)&bu;
        f32x4 z = {0.f, 0.f, 0.f, 0.f};
        f32x4 acc[8];
#pragma unroll
        for (int m = 0; m < 8; ++m)
            acc[m] = __builtin_amdgcn_mfma_f32_16x16x32_bf16(a[m], b, z, 0, 0, 0);
#pragma unroll
        for (int m = 0; m < 8; ++m) {
            unsigned d = __builtin_amdgcn_cvt_pk_fp8_f32(acc[m][0], acc[m][1], 0, false);
            d = __builtin_amdgcn_cvt_pk_fp8_f32(acc[m][2], acc[m][3], d, true);
            *(unsigned*)(myl + rl * 128 + ((m * 16) ^ ((rl & 7) << 4)) + g * 4) = d;
        }
#pragma unroll
        for (int it = 0; it < 2; ++it) {
            int lin = it * 64 + lane;
            int row = lin >> 3, chunk = lin & 7;
            uint4 vv = *(const uint4*)(myl + row * 128 + ((chunk ^ (row & 7)) << 4));
            *(uint4*)&eb[(size_t)tile * 2048 + (size_t)lin * 16] = vv;
        }
        tile = tnext;
        f0 = nf0;
        f1 = nf1;
    }
}

// -------------------------------------------------------------------------
// Kernel: per-node gather-aggregate, 8 edges in flight per wave
// (2 quads of quarter-waves), 8 channels per lane, eb fp8 e-add.
// Output: xs16[node][c] = agg_norm + skip (bf16) — into qb16 space.
// -------------------------------------------------------------------------
__global__ __launch_bounds__(256) void k_aggr3(
    unsigned short* qx,                       // q (read) / xs16 (write) — aliased
    const unsigned short* __restrict__ kvb,
    const unsigned short* __restrict__ skipb16,
    const unsigned char* __restrict__ eb,
    const int2* __restrict__ elist2,
    const int* __restrict__ row_start, const int* __restrict__ row_end)
{
    const int tid = threadIdx.x;
    const int w = tid >> 6, l = tid & 63;
    const int q4 = l >> 4;                    // which edge of the quad
    const int li = l & 15;
    const int c0 = li * 8;                    // this lane's 8 channels

    const int nwaves = gridDim.x * 4;
    for (int node = blockIdx.x * 4 + w; node < NB; node += nwaves) {
        const int rs = row_start[node];
        const int re = row_end[node];
        uint4 qp = *(const uint4*)&qx[(size_t)node * DMODEL + c0];
        const float q0 = bf_lo(qp.x), q1 = bf_hi(qp.x);
        const float q2 = bf_lo(qp.y), q3 = bf_hi(qp.y);
        const float q4_ = bf_lo(qp.z), q5 = bf_hi(qp.z);
        const float q6 = bf_lo(qp.w), q7 = bf_hi(qp.w);
        float a0 = 0.f, a1 = 0.f, a2 = 0.f, a3 = 0.f;
        float a4 = 0.f, a5 = 0.f, a6 = 0.f, a7 = 0.f, den = 0.f;

        for (int j0 = rs; j0 < re; j0 += 8) {
            const int jcA = j0 + q4;
            const int jcB = j0 + 4 + q4;
            const bool actA = jcA < re;        // uniform across 16-lane group
            const bool actB = jcB < re;
            uint4 kpA = make_uint4(0,0,0,0), vpA = make_uint4(0,0,0,0);
            uint4 kpB = make_uint4(0,0,0,0), vpB = make_uint4(0,0,0,0);
            uint2 epA = make_uint2(0,0), epB = make_uint2(0,0);
            if (actA) {
                int2 se = elist2[jcA];
                kpA = *(const uint4*)&kvb[(size_t)se.x * 256 + c0];
                vpA = *(const uint4*)&kvb[(size_t)se.x * 256 + 128 + c0];
                epA = *(const uint2*)&eb[(size_t)se.y * DMODEL + c0];
            }
            if (actB) {
                int2 se = elist2[jcB];
                kpB = *(const uint4*)&kvb[(size_t)se.x * 256 + c0];
                vpB = *(const uint4*)&kvb[(size_t)se.x * 256 + 128 + c0];
                epB = *(const uint2*)&eb[(size_t)se.y * DMODEL + c0];
            }
            // ---- quad A
            {
                f32x2 exl = __builtin_amdgcn_cvt_pk_f32_fp8(epA.x, false);
                f32x2 exh = __builtin_amdgcn_cvt_pk_f32_fp8(epA.x, true);
                f32x2 eyl = __builtin_amdgcn_cvt_pk_f32_fp8(epA.y, false);
                f32x2 eyh = __builtin_amdgcn_cvt_pk_f32_fp8(epA.y, true);
                const float e0 = exl[0], e1 = exl[1], e2 = exh[0], e3 = exh[1];
                const float e4 = eyl[0], e5 = eyl[1], e6 = eyh[0], e7 = eyh[1];
                float p = q0 * (bf_lo(kpA.x) + e0) + q1 * (bf_hi(kpA.x) + e1)
                        + q2 * (bf_lo(kpA.y) + e2) + q3 * (bf_hi(kpA.y) + e3)
                        + q4_ * (bf_lo(kpA.z) + e4) + q5 * (bf_hi(kpA.z) + e5)
                        + q6 * (bf_lo(kpA.w) + e6) + q7 * (bf_hi(kpA.w) + e7);
                p += __shfl_xor(p, 1, 64);
                p += __shfl_xor(p, 2, 64);
                float ea = actA ? __expf(p * 0.17677669529663689f) : 0.f;
                a0 += ea * (bf_lo(vpA.x) + e0);  a1 += ea * (bf_hi(vpA.x) + e1);
                a2 += ea * (bf_lo(vpA.y) + e2);  a3 += ea * (bf_hi(vpA.y) + e3);
                a4 += ea * (bf_lo(vpA.z) + e4);  a5 += ea * (bf_hi(vpA.z) + e5);
                a6 += ea * (bf_lo(vpA.w) + e6);  a7 += ea * (bf_hi(vpA.w) + e7);
                den += ea;
            }
            // ---- quad B
            {
                f32x2 exl = __builtin_amdgcn_cvt_pk_f32_fp8(epB.x, false);
                f32x2 exh = __builtin_amdgcn_cvt_pk_f32_fp8(epB.x, true);
                f32x2 eyl = __builtin_amdgcn_cvt_pk_f32_fp8(epB.y, false);
                f32x2 eyh = __builtin_amdgcn_cvt_pk_f32_fp8(epB.y, true);
                const float e0 = exl[0], e1 = exl[1], e2 = exh[0], e3 = exh[1];
                const float e4 = eyl[0], e5 = eyl[1], e6 = eyh[0], e7 = eyh[1];
                float p = q0 * (bf_lo(kpB.x) + e0) + q1 * (bf_hi(kpB.x) + e1)
                        + q2 * (bf_lo(kpB.y) + e2) + q3 * (bf_hi(kpB.y) + e3)
                        + q4_ * (bf_lo(kpB.z) + e4) + q5 * (bf_hi(kpB.z) + e5)
                        + q6 * (bf_lo(kpB.w) + e6) + q7 * (bf_hi(kpB.w) + e7);
                p += __shfl_xor(p, 1, 64);
                p += __shfl_xor(p, 2, 64);
                float ea = actB ? __expf(p * 0.17677669529663689f) : 0.f;
                a0 += ea * (bf_lo(vpB.x) + e0);  a1 += ea * (bf_hi(vpB.x) + e1);
                a2 += ea * (bf_lo(vpB.y) + e2);  a3 += ea * (bf_hi(vpB.y) + e3);
                a4 += ea * (bf_lo(vpB.z) + e4);  a5 += ea * (bf_hi(vpB.z) + e5);
                a6 += ea * (bf_lo(vpB.w) + e6);  a7 += ea * (bf_hi(vpB.w) + e7);
                den += ea;
            }
        }
        // combine the four quarter-wave edge streams
#pragma unroll
        for (int off = 16; off <= 32; off <<= 1) {
            a0 += __shfl_xor(a0, off, 64);  a1 += __shfl_xor(a1, off, 64);
            a2 += __shfl_xor(a2, off, 64);  a3 += __shfl_xor(a3, off, 64);
            a4 += __shfl_xor(a4, off, 64);  a5 += __shfl_xor(a5, off, 64);
            a6 += __shfl_xor(a6, off, 64);  a7 += __shfl_xor(a7, off, 64);
            den += __shfl_xor(den, off, 64);
        }
        float r = 1.0f / (den + 1e-16f);
        if (q4 == 0) {
            uint4 sp = *(const uint4*)&skipb16[(size_t)node * DMODEL + c0];
            uint4 o;
            o.x = pack_bf16x2(a0 * r + bf_lo(sp.x), a1 * r + bf_hi(sp.x));
            o.y = pack_bf16x2(a2 * r + bf_lo(sp.y), a3 * r + bf_hi(sp.y));
            o.z = pack_bf16x2(a4 * r + bf_lo(sp.z), a5 * r + bf_hi(sp.z));
            o.w = pack_bf16x2(a6 * r + bf_lo(sp.w), a7 * r + bf_hi(sp.w));
            *(uint4*)&qx[(size_t)node * DMODEL + c0] = o;
        }
    }
}

// -------------------------------------------------------------------------
// Kernel (MFMA): FFN on xs16 (= agg_norm + skip, bf16) + transposed write.
// -------------------------------------------------------------------------
#define H1_OFF 16384

__global__ __launch_bounds__(256) void k_ffn_mfma(
    const unsigned short* __restrict__ xs16,
    const uint4* __restrict__ w1f, const float* __restrict__ b1,
    const uint4* __restrict__ w2f, const float* __restrict__ b2,
    float* __restrict__ out)
{
    __shared__ __align__(16) char lds[49152];
    const int tid   = threadIdx.x;
    const int node0 = blockIdx.x * 64;

#pragma unroll
    for (int i = 0; i < 4; ++i) {
        int linear = i * 256 + tid;
        int row = linear >> 4;
        int c8  = (linear & 15) * 8;
        int node = node0 + row;
        uint4 vv = (node < NB) ? *(const uint4*)&xs16[(size_t)node * DMODEL + c8]
                               : make_uint4(0, 0, 0, 0);
        int byte = row * 256 + ((c8 * 2) ^ ((row & 7) << 4));
        *(uint4*)(&lds[byte]) = vv;
    }
    __syncthreads();

    const int w = tid >> 6, lane = tid & 63;
    const int rl = lane & 15, g = lane >> 4;

    // ---- GEMM1: wave w covers col1 in [w*64, w*64+64)
    {
        f32x4 acc[4][4] = {};
#pragma unroll
        for (int ks = 0; ks < 4; ++ks) {
            bf16x8 a[4], b[4];
#pragma unroll
            for (int mt = 0; mt < 4; ++mt) {
                int m1 = w * 4 + mt;
                a[mt] = *(const bf16x8*)&w1f[(m1 * 4 + ks) * 64 + lane];
            }
#pragma unroll
            for (int nt = 0; nt < 4; ++nt) {
                int node = nt * 16 + rl;
                int byte = node * 256 + ((ks * 64 + g * 16) ^ ((node & 7) << 4));
                b[nt] = *(const bf16x8*)&lds[byte];
            }
#pragma unroll
            for (int mt = 0; mt < 4; ++mt)
#pragma unroll
                for (int nt = 0; nt < 4; ++nt)
                    acc[mt][nt] = __builtin_amdgcn_mfma_f32_16x16x32_bf16(
                        a[mt], b[nt], acc[mt][nt], 0, 0, 0);
        }
#pragma unroll
        for (int mt = 0; mt < 4; ++mt) {
            int col1_0 = w * 64 + mt * 16 + g * 4;
            float bb0 = b1[col1_0], bb1 = b1[col1_0 + 1],
                  bb2 = b1[col1_0 + 2], bb3 = b1[col1_0 + 3];
#pragma unroll
            for (int nt = 0; nt < 4; ++nt) {
                int node = nt * 16 + rl;
                float v0 = fmaxf(acc[mt][nt][0] + bb0, 0.f);
                float v1 = fmaxf(acc[mt][nt][1] + bb1, 0.f);
                float v2 = fmaxf(acc[mt][nt][2] + bb2, 0.f);
                float v3 = fmaxf(acc[mt][nt][3] + bb3, 0.f);
                unsigned lo = pack_bf16x2(v0, v1), hi = pack_bf16x2(v2, v3);
                int byte = H1_OFF + node * 512 + ((col1_0 * 2) ^ ((node & 7) << 4));
                *(uint2*)(&lds[byte]) = make_uint2(lo, hi);
            }
        }
    }
    __syncthreads();

    // ---- GEMM2: wave w covers c2 in [w*32, w*32+32)
    {
        f32x4 acc[2][4] = {};
#pragma unroll
        for (int ks = 0; ks < 8; ++ks) {
            bf16x8 a[2], b[4];
#pragma unroll
            for (int mt = 0; mt < 2; ++mt) {
                int m2 = w * 2 + mt;
                a[mt] = *(const bf16x8*)&w2f[(m2 * 8 + ks) * 64 + lane];
            }
#pragma unroll
            for (int nt = 0; nt < 4; ++nt) {
                int node = nt * 16 + rl;
                int byte = H1_OFF + node * 512 + ((ks * 64 + g * 16) ^ ((node & 7) << 4));
                b[nt] = *(const bf16x8*)&lds[byte];
            }
#pragma unroll
            for (int mt = 0; mt < 2; ++mt)
#pragma unroll
                for (int nt = 0; nt < 4; ++nt)
                    acc[mt][nt] = __builtin_amdgcn_mfma_f32_16x16x32_bf16(
                        a[mt], b[nt], acc[mt][nt], 0, 0, 0);
        }
#pragma unroll
        for (int mt = 0; mt < 2; ++mt) {
            int c2_0 = w * 32 + mt * 16 + g * 4;
#pragma unroll
            for (int nt = 0; nt < 4; ++nt) {
                int node = node0 + nt * 16 + rl;
                if (node < NB) {
                    int bb = node / NPB;
                    int nn = node - bb * NPB;
                    size_t base = (size_t)(bb * DMODEL) * NPB + nn;
#pragma unroll
                    for (int r = 0; r < 4; ++r) {
                        float v = fmaxf(acc[mt][nt][r] + b2[c2_0 + r], 0.f);
                        out[base + (size_t)(c2_0 + r) * NPB] = v;
                    }
                }
            }
        }
    }
}

// -------------------------------------------------------------------------
extern "C" void kernel_launch(void* const* d_in, const int* in_sizes, int n_in,
                              void* d_out, int out_size, void* d_ws, size_t ws_size,
                              hipStream_t stream)
{
    const float* x     = (const float*)d_in[0];
    const int*   eidx  = (const int*)  d_in[1];
    const float* eattr = (const float*)d_in[2];
    const float* Wq    = (const float*)d_in[3];
    const float* bq    = (const float*)d_in[4];
    const float* Wk    = (const float*)d_in[5];
    const float* bk    = (const float*)d_in[6];
    const float* Wv    = (const float*)d_in[7];
    const float* bv    = (const float*)d_in[8];
    const float* We    = (const float*)d_in[9];
    const float* Wskip = (const float*)d_in[10];
    const float* bskip = (const float*)d_in[11];
    const float* W1    = (const float*)d_in[12];
    const float* b1    = (const float*)d_in[13];
    const float* W2    = (const float*)d_in[14];
    const float* b2    = (const float*)d_in[15];
    float* out = (float*)d_out;

    // ws layout (~212.9 MB, proven budget):
    // qb16(->xs16) | kvb | skipb16 | eb fp8 | w1f | w2f | wef | wpf |
    // counts | row_start | cursor | elist2 | bsum
    const size_t NBD = (size_t)NB * DMODEL;
    unsigned short* qb16    = (unsigned short*)d_ws;
    unsigned short* kvb     = qb16 + NBD;
    unsigned short* skipb16 = kvb + 2 * NBD;
    unsigned char*  eb      = (unsigned char*)(skipb16 + NBD);
    uint4* w1f = (uint4*)(eb + (size_t)T_E * DMODEL);
    uint4* w2f = w1f + 64 * 64;
    uint4* wef = w2f + 64 * 64;
    uint4* wpf = wef + 8 * 64;
    int* counts    = (int*)(wpf + 128 * 64);
    int* row_start = counts + NB;
    int* cursor    = row_start + NB;
    int2* elist2   = (int2*)(cursor + NB);
    int* bsum      = (int*)(elist2 + T_E);

    k_prep<<<66, 256, 0, stream>>>(W1, W2, We, Wq, Wk, Wv, Wskip,
                                   w1f, w2f, wef, wpf, counts);
    k_proj2<<<(NB + 63) / 64, 256, 0, stream>>>(x, wpf, bq, bk, bv, bskip,
                                                qb16, kvb, skipb16);
    k_hist<<<(T_E + 255) / 256, 256, 0, stream>>>(eidx, counts);
    k_scan1<<<SCAN_NBLK, 1024, 0, stream>>>(counts, row_start, bsum);
    k_scan2<<<1, 128, 0, stream>>>(bsum);
    k_scan3<<<SCAN_NBLK, 1024, 0, stream>>>(row_start, bsum, cursor);
    k_scatter<<<(T_E + 255) / 256, 256, 0, stream>>>(eidx, cursor, elist2);
    k_eproj<<<2048, 256, 0, stream>>>(eattr, wef, eb);
    k_aggr3<<<2048, 256, 0, stream>>>(qb16, kvb, skipb16, eb, elist2,
                                      row_start, cursor);
    k_ffn_mfma<<<(NB + 63) / 64, 256, 0, stream>>>(qb16, w1f, b1, w2f, b2, out);
}